// Round 1
// 145.517 us; speedup vs baseline: 1.0347x; 1.0347x over previous
//
#include <hip/hip_runtime.h>

// out[b] = (x @ W^T).sum(axis=1) * (0.5 * 2.0) = sum_k x[b,k] * wsum[k],
// with wsum[k] = sum_h W[h,k].
// Three deterministic memory-bound passes; NO atomics (R1: 256-way atomicAdd
// contention made colsum 3x slower than its BW floor).
//
// R2 changes vs 149us version:
//  - stage2: 4 blocks -> 16 blocks (was parallelism-starved on 4 CUs reading
//    partials scattered across all 8 XCD L2s)
//  - stage3: 4 rows/block with wsum held in registers across rows
//    (cuts wsum L2 re-read traffic 64MiB -> 16MiB, 4x the per-thread MLP,
//    1/4 the block-reduction overhead)

#define N 4096            // BATCH == INPUT_SIZE == HIDDEN_SIZE
#define N4 (N / 4)        // float4 elements per row
#define P 128             // row partitions for partial column sums
#define ROWS (N / P)      // 32 rows per partial block
#define R3 4              // rows per block in stage 3

// Stage 1: partial[p][k] = sum over 32 rows of W[., k].  Plain stores, no atomics.
// grid (4, 128) = 512 blocks (2/CU); each thread owns one float4 column,
// 32 independent dwordx4 loads -> deep MLP, coalesced 1 KiB/wave/iter.
__global__ __launch_bounds__(256) void colsum_partial_kernel(
    const float* __restrict__ W, float* __restrict__ partial) {
    const int col4 = blockIdx.x * 256 + threadIdx.x;
    const int row0 = blockIdx.y * ROWS;
    const float4* __restrict__ W4 = (const float4*)W;

    float4 acc = make_float4(0.f, 0.f, 0.f, 0.f);
#pragma unroll
    for (int r = 0; r < ROWS; ++r) {
        float4 v = W4[(size_t)(row0 + r) * N4 + col4];
        acc.x += v.x; acc.y += v.y; acc.z += v.z; acc.w += v.w;
    }
    ((float4*)partial)[(size_t)blockIdx.y * N4 + col4] = acc;
}

// Stage 2: wsum[k] = sum_p partial[p][k].
// 16 blocks x 256 threads: each block owns 64 float4 columns; the 4 wave-rows
// of the block each sum 32 of the 128 partials, then a 4-way LDS combine.
// Spreads the 2 MiB read over 16 CUs instead of 4.
__global__ __launch_bounds__(256) void colsum_reduce_kernel(
    const float* __restrict__ partial, float* __restrict__ wsum) {
    const int lane = threadIdx.x & 63;         // col4 within block's 64-column slab
    const int pg   = threadIdx.x >> 6;         // partial group 0..3
    const int col4 = blockIdx.x * 64 + lane;
    const float4* __restrict__ p4 = (const float4*)partial;

    float4 acc = make_float4(0.f, 0.f, 0.f, 0.f);
#pragma unroll
    for (int p = 0; p < P / 4; ++p) {
        float4 v = p4[(size_t)(pg * (P / 4) + p) * N4 + col4];
        acc.x += v.x; acc.y += v.y; acc.z += v.z; acc.w += v.w;
    }

    __shared__ float4 s[4][64];
    s[pg][lane] = acc;
    __syncthreads();
    if (threadIdx.x < 64) {
        float4 a = s[0][lane], b = s[1][lane], c = s[2][lane], d = s[3][lane];
        float4 r;
        r.x = (a.x + b.x) + (c.x + d.x);
        r.y = (a.y + b.y) + (c.y + d.y);
        r.z = (a.z + b.z) + (c.z + d.z);
        r.w = (a.w + b.w) + (c.w + d.w);
        ((float4*)wsum)[col4] = r;
    }
}

// Stage 3: out[b] = dot(x[b,:], wsum).  4 rows per 256-thread block (1024
// blocks); each wsum float4 is loaded once and reused for all 4 rows.
__global__ __launch_bounds__(256) void rowdot_kernel(
    const float* __restrict__ x, const float* __restrict__ wsum,
    float* __restrict__ out) {
    const int b0 = blockIdx.x * R3;
    const int tid = threadIdx.x;
    const float4* __restrict__ w4 = (const float4*)wsum;
    const float4* __restrict__ x4 = (const float4*)x;

    float acc[R3] = {0.f, 0.f, 0.f, 0.f};
#pragma unroll
    for (int i = 0; i < N4 / 256; ++i) {        // 4 iterations
        const int c = i * 256 + tid;
        const float4 wv = w4[c];
#pragma unroll
        for (int r = 0; r < R3; ++r) {
            float4 xv = x4[(size_t)(b0 + r) * N4 + c];
            acc[r] += xv.x * wv.x + xv.y * wv.y + xv.z * wv.z + xv.w * wv.w;
        }
    }

    // wave64 shuffle reduction per row, then cross-wave LDS combine
    __shared__ float sl[4][R3];
    const int lane = tid & 63;
    const int wave = tid >> 6;
#pragma unroll
    for (int r = 0; r < R3; ++r) {
        float a = acc[r];
#pragma unroll
        for (int off = 32; off > 0; off >>= 1)
            a += __shfl_down(a, off, 64);
        if (lane == 0) sl[wave][r] = a;
    }
    __syncthreads();
    if (tid < R3)
        out[b0 + tid] =
            (sl[0][tid] + sl[1][tid] + sl[2][tid] + sl[3][tid]) * (0.5f * 2.0f);
}

extern "C" void kernel_launch(void* const* d_in, const int* in_sizes, int n_in,
                              void* d_out, int out_size, void* d_ws, size_t ws_size,
                              hipStream_t stream) {
    const float* x = (const float*)d_in[0];       // (4096, 4096) fp32
    const float* W = (const float*)d_in[1];       // (4096, 4096) fp32
    float* out = (float*)d_out;                   // (4096, 1) fp32

    float* partial = (float*)d_ws;                            // P * N floats = 2 MiB
    float* wsum = (float*)((char*)d_ws + (size_t)P * N * 4);  // N floats, 16B-aligned

    dim3 grid1(N4 / 256, P);                      // (4, 128) = 512 blocks
    colsum_partial_kernel<<<grid1, 256, 0, stream>>>(W, partial);

    colsum_reduce_kernel<<<N4 / 64, 256, 0, stream>>>(partial, wsum);   // 16 blocks

    rowdot_kernel<<<N / R3, 256, 0, stream>>>(x, wsum, out);            // 1024 blocks
}